// Round 1
// baseline (92.247 us; speedup 1.0000x reference)
//
#include <hip/hip_runtime.h>
#include <math.h>

#define BS 8
#define NR 60
#define NRP 30                // rotation pairs per batch
#define NP 500
#define NHW 6400
#define NPAIR (BS*NR)         // 480 (b,r) pairs
#define NBLK (BS*NRP)         // 240 blocks, one per (b, rot-pair)
#define NT_ELEMS (BS*NP*3)    // 12000
#define LT_PER_BLK 50         // 240*50 = 12000

#define BIGF 3.4e38f

// Module-scope completion counter. Lives in module .data (NOT the poisoned
// workspace), never reset: each full grid adds exactly NBLK, so the block
// whose atomicAdd returns old % NBLK == NBLK-1 is the last of THIS launch.
// Works across graph replays / rocprof replays without a memset node.
__device__ unsigned int g_ctr = 0u;

// 240 blocks x 512 threads. Block = (b, rotation-pair).
// Lane l owns points {l, l+64, ..., l+448} (8 slots) for both rotations;
// wave w processes only its m-eighth of the 500 targets. The m-loop is
// unrolled by 2 so the two fresh distances + accumulator fuse into one
// v_min3_f32 (7 VALU per 2m per point per rot instead of 8).
// The final cross-pair reduction is fused in as a last-block-done tail
// (saves the second dispatch + full-device drain).
__global__ __launch_bounds__(512) void main_kernel(
    const float* __restrict__ pred_t,        // (8,500,3)
    const float* __restrict__ pred_r,        // (8,60,4)
    const float* __restrict__ target_r,      // (8,1,500,3)
    const float* __restrict__ target_t,      // (8,3,6400)
    const float* __restrict__ model_points,  // (8,1,500,3)
    const int*   __restrict__ choose,        // (8,500)
    const float* __restrict__ rot_anchors,   // (60,4)
    const float* __restrict__ pred_c,        // (8,60)
    const unsigned char* __restrict__ symU8, // (8) bool, layout-agnostic read
    const int*   __restrict__ symI,
    const float* __restrict__ diam,          // (8)
    float* __restrict__ out_sym,             // ws: 480 (indexed by pair)
    float* __restrict__ out_non,             // ws: 480
    float* __restrict__ out_reg,             // ws: 480
    float* __restrict__ out_lt,              // ws: 240 (per block)
    float* __restrict__ out)                 // 4 floats
{
    const int bid = blockIdx.x;
    const int b  = bid / NRP;
    const int rp = bid % NRP;
    const int r0 = 2 * rp, r1 = 2 * rp + 1;
    const int pair0 = b * NR + r0;           // pair1 = pair0 + 1
    const int tid = threadIdx.x;
    const int wv = tid >> 6;                 // wave 0..7
    const int ln = tid & 63;                 // lane 0..63

    __shared__ float4 t4s[NP];               // {x,y,z,|t|^2} — 8000 B
    __shared__ float2 part2[8 * 8 * 64];     // [w][slot][lane]{rotA,rotB} — 32 KB
    __shared__ unsigned int s_last;

    // layout-agnostic bool read (true under 1-byte-bool and int32 storage)
    const bool symb = (symU8[b] != 0) || (symI[b] != 0);

    // --- stage target points global -> LDS, fusing |t|^2 ---
    if (tid < NP) {
        const float* p = target_r + (b * NP + tid) * 3;
        float x = p[0], y = p[1], z = p[2];
        t4s[tid] = make_float4(x, y, z, x * x + y * y + z * z);
    }

    // --- two quaternions -> rotation matrices ---
    const float* q0p = pred_r + pair0 * 4;
    const float w0 = q0p[0], x0 = q0p[1], y0 = q0p[2], z0 = q0p[3];
    const float w1 = q0p[4], x1 = q0p[5], y1 = q0p[6], z1 = q0p[7];

    const float A00 = 1.f - 2.f * (y0 * y0 + z0 * z0);
    const float A01 = 2.f * x0 * y0 - 2.f * w0 * z0;
    const float A02 = 2.f * w0 * y0 + 2.f * x0 * z0;
    const float A10 = 2.f * x0 * y0 + 2.f * z0 * w0;
    const float A11 = 1.f - 2.f * (x0 * x0 + z0 * z0);
    const float A12 = -2.f * w0 * x0 + 2.f * y0 * z0;
    const float A20 = -2.f * w0 * y0 + 2.f * x0 * z0;
    const float A21 = 2.f * w0 * x0 + 2.f * y0 * z0;
    const float A22 = 1.f - 2.f * (x0 * x0 + y0 * y0);

    const float B00 = 1.f - 2.f * (y1 * y1 + z1 * z1);
    const float B01 = 2.f * x1 * y1 - 2.f * w1 * z1;
    const float B02 = 2.f * w1 * y1 + 2.f * x1 * z1;
    const float B10 = 2.f * x1 * y1 + 2.f * z1 * w1;
    const float B11 = 1.f - 2.f * (x1 * x1 + z1 * z1);
    const float B12 = -2.f * w1 * x1 + 2.f * y1 * z1;
    const float B20 = -2.f * w1 * y1 + 2.f * x1 * z1;
    const float B21 = 2.f * w1 * x1 + 2.f * y1 * z1;
    const float B22 = 1.f - 2.f * (x1 * x1 + y1 * y1);

    // --- loss_t partial: 50 scattered elements per block (wave 0) ---
    float lt = 0.f;
    if (tid < LT_PER_BLK) {
        int e = bid * LT_PER_BLK + tid;      // flat index into pred_t (8,500,3)
        int bb = e / 1500;
        int rem = e - bb * 1500;
        int n = rem / 3;
        int k = rem - n * 3;
        int pos = choose[bb * NP + n];
        float ts = target_t[(bb * 3 + k) * NHW + pos];
        float diff = pred_t[e] - ts;
        float ad = fabsf(diff);
        lt = (ad < 1.f) ? 0.5f * diff * diff : ad - 0.5f;
    }

    // --- reg term: wave 0 handles r0 (+lt reduce), wave 1 handles r1 ---
    if (tid < 64) {
        float dot = -BIGF;
        if (tid < NR) {
            const float* an = rot_anchors + tid * 4;
            dot = w0 * an[0] + x0 * an[1] + y0 * an[2] + z0 * an[3];
        }
        float diag = __shfl(dot, r0, 64);
        float mx = dot;
        for (int o = 32; o > 0; o >>= 1) mx = fmaxf(mx, __shfl_down(mx, o, 64));
        for (int o = 32; o > 0; o >>= 1) lt += __shfl_down(lt, o, 64);
        if (tid == 0) {
            float rg = mx - diag;
            out_reg[pair0] = (rg > 0.001f) ? rg : 0.f;
            out_lt[bid] = lt;
        }
    } else if (tid < 128) {
        float dot = -BIGF;
        if (ln < NR) {
            const float* an = rot_anchors + ln * 4;
            dot = w1 * an[0] + x1 * an[1] + y1 * an[2] + z1 * an[3];
        }
        float diag = __shfl(dot, r1, 64);
        float mx = dot;
        for (int o = 32; o > 0; o >>= 1) mx = fmaxf(mx, __shfl_down(mx, o, 64));
        if (ln == 0) {
            float rg = mx - diag;
            out_reg[pair0 + 1] = (rg > 0.001f) ? rg : 0.f;
        }
    }

    // --- rotate the 8 owned model points for both rotations; keep -2*p ---
    float nAx[8], nAy[8], nAz[8], nBx[8], nBy[8], nBz[8];
    const float* mpb = model_points + b * NP * 3;
#pragma unroll
    for (int k = 0; k < 8; ++k) {
        int pt = k * 64 + ln;
        int pc = (pt < NP) ? pt : 0;         // clamp; masked at combine
        float mx_ = mpb[pc * 3 + 0], my_ = mpb[pc * 3 + 1], mz_ = mpb[pc * 3 + 2];
        float pax = A00 * mx_ + A01 * my_ + A02 * mz_;
        float pay = A10 * mx_ + A11 * my_ + A12 * mz_;
        float paz = A20 * mx_ + A21 * my_ + A22 * mz_;
        float pbx = B00 * mx_ + B01 * my_ + B02 * mz_;
        float pby = B10 * mx_ + B11 * my_ + B12 * mz_;
        float pbz = B20 * mx_ + B21 * my_ + B22 * mz_;
        nAx[k] = -2.f * pax; nAy[k] = -2.f * pay; nAz[k] = -2.f * paz;
        nBx[k] = -2.f * pbx; nBy[k] = -2.f * pby; nBz[k] = -2.f * pbz;
    }

    __syncthreads();                          // t4s ready

    // --- main loop: this wave's m-eighth, unrolled x2 for v_min3 fusion ---
    const int mstart = (wv * NP) >> 3;
    const int mend   = ((wv + 1) * NP) >> 3;
    float mnA[8], mnB[8];
#pragma unroll
    for (int k = 0; k < 8; ++k) { mnA[k] = BIGF; mnB[k] = BIGF; }

    int m = mstart;
    for (; m + 1 < mend; m += 2) {
        float4 t0 = t4s[m];                   // wave-uniform -> broadcast
        float4 t1 = t4s[m + 1];
#pragma unroll
        for (int k = 0; k < 8; ++k) {
            float dA0 = fmaf(nAx[k], t0.x, fmaf(nAy[k], t0.y, fmaf(nAz[k], t0.z, t0.w)));
            float dA1 = fmaf(nAx[k], t1.x, fmaf(nAy[k], t1.y, fmaf(nAz[k], t1.z, t1.w)));
            mnA[k] = fminf(mnA[k], fminf(dA0, dA1));   // -> v_min3_f32
            float dB0 = fmaf(nBx[k], t0.x, fmaf(nBy[k], t0.y, fmaf(nBz[k], t0.z, t0.w)));
            float dB1 = fmaf(nBx[k], t1.x, fmaf(nBy[k], t1.y, fmaf(nBz[k], t1.z, t1.w)));
            mnB[k] = fminf(mnB[k], fminf(dB0, dB1));
        }
    }
    if (m < mend) {                           // odd-count tail
        float4 t = t4s[m];
#pragma unroll
        for (int k = 0; k < 8; ++k) {
            float dA = fmaf(nAx[k], t.x, fmaf(nAy[k], t.y, fmaf(nAz[k], t.z, t.w)));
            mnA[k] = fminf(mnA[k], dA);
            float dB = fmaf(nBx[k], t.x, fmaf(nBy[k], t.y, fmaf(nBz[k], t.z, t.w)));
            mnB[k] = fminf(mnB[k], dB);
        }
    }

    // --- publish partial mins ---
#pragma unroll
    for (int k = 0; k < 8; ++k)
        part2[(wv * 8 + k) * 64 + ln] = make_float2(mnA[k], mnB[k]);
    __syncthreads();

    // --- combine: wave 0 -> rotation A, wave 1 -> rotation B ---
    if (wv < 2) {
        const float* partf = (const float*)part2;
        float symsum = 0.f, nonsum = 0.f;
#pragma unroll
        for (int k = 0; k < 8; ++k) {
            float mn = BIGF;
#pragma unroll
            for (int w2 = 0; w2 < 8; ++w2) {
                float v = partf[((w2 * 8 + k) * 64 + ln) * 2 + wv];  // 2-way stride: free
                mn = fminf(mn, v);
            }
            float px = -0.5f * ((wv == 0) ? nAx[k] : nBx[k]);
            float py = -0.5f * ((wv == 0) ? nAy[k] : nBy[k]);
            float pz = -0.5f * ((wv == 0) ? nAz[k] : nBz[k]);
            float a2 = px * px + py * py + pz * pz;
            int pt = k * 64 + ln;
            if (pt < NP) {
                float d2 = fmaxf(a2 + mn, 1e-12f);
                symsum += sqrtf(d2);
                if (!symb) {                  // only needed when not symmetric
                    float4 t = t4s[pt];
                    float dx = px - t.x, dy = py - t.y, dz = pz - t.z;
                    nonsum += sqrtf(dx * dx + dy * dy + dz * dz);
                }
            }
        }
        for (int o = 32; o > 0; o >>= 1) {
            symsum += __shfl_down(symsum, o, 64);
            nonsum += __shfl_down(nonsum, o, 64);
        }
        if (ln == 0) {
            out_sym[pair0 + wv] = symsum;
            if (!symb) out_non[pair0 + wv] = nonsum;  // unread when symb
        }
    }

    // ================= fused finalize (last-block-done) =================
    __syncthreads();                          // all this block's stores issued+drained
    if (tid == 0) {
        __threadfence();                      // release: make partials device-visible
        unsigned int old = atomicAdd(&g_ctr, 1u);
        s_last = ((old % NBLK) == (NBLK - 1)) ? 1u : 0u;
    }
    __syncthreads();
    if (s_last == 0u) return;

    __threadfence();                          // acquire: invalidate stale L1/L2 lines
    float s_r = 0.f, s_reg = 0.f, s_t = 0.f;
    if (tid < NPAIR) {                        // 480 < 512: one element per thread
        int bb2 = tid / NR;
        bool sym2 = (symU8[bb2] != 0) || (symI[bb2] != 0);
        float sum = sym2 ? out_sym[tid] : out_non[tid];
        float dd = sum * (1.0f / NP);
        float c = pred_c[tid];
        s_r = (dd / (diam[bb2] * c) + logf(c)) * (1.0f / NR);
        s_reg = out_reg[tid];
    }
    if (tid < NBLK) s_t = out_lt[tid];

    for (int o = 32; o > 0; o >>= 1) {
        s_r  += __shfl_down(s_r, o, 64);
        s_reg += __shfl_down(s_reg, o, 64);
        s_t  += __shfl_down(s_t, o, 64);
    }
    float* red = (float*)part2;               // reuse LDS (safe: past all readers)
    if (ln == 0) { red[wv] = s_r; red[8 + wv] = s_reg; red[16 + wv] = s_t; }
    __syncthreads();
    if (tid == 0) {
        float lr = 0.f, lreg = 0.f, ltv = 0.f;
#pragma unroll
        for (int w2 = 0; w2 < 8; ++w2) {
            lr += red[w2]; lreg += red[8 + w2]; ltv += red[16 + w2];
        }
        lreg *= (1.0f / NPAIR);
        ltv  *= (1.0f / NT_ELEMS);
        out[0] = lr + 2.f * lreg + 5.f * ltv;
        out[1] = lr;
        out[2] = lreg;
        out[3] = ltv;
    }
}

extern "C" void kernel_launch(void* const* d_in, const int* in_sizes, int n_in,
                              void* d_out, int out_size, void* d_ws, size_t ws_size,
                              hipStream_t stream) {
    const float* pred_t       = (const float*)d_in[0];
    const float* pred_r       = (const float*)d_in[1];
    const float* pred_c       = (const float*)d_in[2];
    const float* target_r     = (const float*)d_in[3];
    const float* target_t     = (const float*)d_in[4];
    const float* model_points = (const float*)d_in[5];
    const int*   choose       = (const int*)d_in[6];
    const unsigned char* symU8 = (const unsigned char*)d_in[7];
    const int*   symI         = (const int*)d_in[7];
    const float* diam         = (const float*)d_in[8];
    const float* anchors      = (const float*)d_in[9];
    float* out = (float*)d_out;

    char* ws = (char*)d_ws;
    float* o_sym = (float*)ws;                        // 480 floats
    float* o_non = o_sym + NPAIR;                     // 480
    float* o_reg = o_non + NPAIR;                     // 480
    float* o_lt  = o_reg + NPAIR;                     // 240

    main_kernel<<<NBLK, 512, 0, stream>>>(pred_t, pred_r, target_r, target_t,
                                          model_points, choose, anchors,
                                          pred_c, symU8, symI, diam,
                                          o_sym, o_non, o_reg, o_lt, out);
}

// Round 2
// 90.326 us; speedup vs baseline: 1.0213x; 1.0213x over previous
//
#include <hip/hip_runtime.h>
#include <math.h>

#define BS 8
#define NR 60
#define NRP 30                // rotation pairs per batch
#define NP 500
#define NHW 6400
#define NPAIR (BS*NR)         // 480 (b,r) pairs
#define NBLK (BS*NRP)         // 240 blocks, one per (b, rot-pair)
#define NT_ELEMS (BS*NP*3)    // 12000
#define LT_PER_BLK 50         // 240*50 = 12000

#define BIGF 3.4e38f

typedef float v2f __attribute__((ext_vector_type(2)));

// packed fp32 FMA -> v_pk_fma_f32 on gfx950 (FeaturePackedFP32Ops).
// Fallback a*b+c contracts to the same instruction under HIP's default
// -ffp-contract=fast; worst case it scalarizes to 2x v_fma (neutral).
#if __has_builtin(__builtin_elementwise_fma)
#define PKFMA(a,b,c) __builtin_elementwise_fma((a),(b),(c))
#else
#define PKFMA(a,b,c) ((a)*(b)+(c))
#endif

// Module-scope completion counter. Lives in module .data (NOT the poisoned
// workspace), never reset: each full grid adds exactly NBLK, so the block
// whose atomicAdd returns old % NBLK == NBLK-1 is the last of THIS launch.
// Works across graph replays / rocprof replays without a memset node.
__device__ unsigned int g_ctr = 0u;

// 240 blocks x 512 threads. Block = (b, rotation-pair).
// Lane l owns points {l, l+64, ..., l+448} (8 slots) for both rotations;
// wave w processes only its m-slice of the 500 targets (62/62/62/62/62/62/
// 64/64 — all even, so the 2-wide packed loop has no tail).
// Hot loop uses v_pk_fma_f32 over k-pairs: the per-lane rotated-point
// constants are stored as v2f pairs (natural VGPR pairs, no splat cost);
// only the 4 wave-uniform t components are splatted per m (hoistable to
// op_sel by the backend). Mins stay scalar (no v_pk_min_f32 on CDNA) and
// fuse to v_min3_f32 across the 2-m unroll.
__global__ __launch_bounds__(512) void main_kernel(
    const float* __restrict__ pred_t,        // (8,500,3)
    const float* __restrict__ pred_r,        // (8,60,4)
    const float* __restrict__ target_r,      // (8,1,500,3)
    const float* __restrict__ target_t,      // (8,3,6400)
    const float* __restrict__ model_points,  // (8,1,500,3)
    const int*   __restrict__ choose,        // (8,500)
    const float* __restrict__ rot_anchors,   // (60,4)
    const float* __restrict__ pred_c,        // (8,60)
    const unsigned char* __restrict__ symU8, // (8) bool, layout-agnostic read
    const int*   __restrict__ symI,
    const float* __restrict__ diam,          // (8)
    float* __restrict__ out_sym,             // ws: 480 (indexed by pair)
    float* __restrict__ out_non,             // ws: 480
    float* __restrict__ out_reg,             // ws: 480
    float* __restrict__ out_lt,              // ws: 240 (per block)
    float* __restrict__ out)                 // 4 floats
{
    const int bid = blockIdx.x;
    const int b  = bid / NRP;
    const int rp = bid % NRP;
    const int r0 = 2 * rp, r1 = 2 * rp + 1;
    const int pair0 = b * NR + r0;           // pair1 = pair0 + 1
    const int tid = threadIdx.x;
    const int wv = tid >> 6;                 // wave 0..7
    const int ln = tid & 63;                 // lane 0..63

    __shared__ float4 t4s[NP];               // {x,y,z,|t|^2} — 8000 B
    __shared__ float2 part2[8 * 8 * 64];     // [w][slot][lane]{rotA,rotB} — 32 KB
    __shared__ unsigned int s_last;

    // layout-agnostic bool read (true under 1-byte-bool and int32 storage)
    const bool symb = (symU8[b] != 0) || (symI[b] != 0);

    // --- stage target points global -> LDS, fusing |t|^2 ---
    if (tid < NP) {
        const float* p = target_r + (b * NP + tid) * 3;
        float x = p[0], y = p[1], z = p[2];
        t4s[tid] = make_float4(x, y, z, x * x + y * y + z * z);
    }

    // --- two quaternions -> rotation matrices ---
    const float* q0p = pred_r + pair0 * 4;
    const float w0 = q0p[0], x0 = q0p[1], y0 = q0p[2], z0 = q0p[3];
    const float w1 = q0p[4], x1 = q0p[5], y1 = q0p[6], z1 = q0p[7];

    const float A00 = 1.f - 2.f * (y0 * y0 + z0 * z0);
    const float A01 = 2.f * x0 * y0 - 2.f * w0 * z0;
    const float A02 = 2.f * w0 * y0 + 2.f * x0 * z0;
    const float A10 = 2.f * x0 * y0 + 2.f * z0 * w0;
    const float A11 = 1.f - 2.f * (x0 * x0 + z0 * z0);
    const float A12 = -2.f * w0 * x0 + 2.f * y0 * z0;
    const float A20 = -2.f * w0 * y0 + 2.f * x0 * z0;
    const float A21 = 2.f * w0 * x0 + 2.f * y0 * z0;
    const float A22 = 1.f - 2.f * (x0 * x0 + y0 * y0);

    const float B00 = 1.f - 2.f * (y1 * y1 + z1 * z1);
    const float B01 = 2.f * x1 * y1 - 2.f * w1 * z1;
    const float B02 = 2.f * w1 * y1 + 2.f * x1 * z1;
    const float B10 = 2.f * x1 * y1 + 2.f * z1 * w1;
    const float B11 = 1.f - 2.f * (x1 * x1 + z1 * z1);
    const float B12 = -2.f * w1 * x1 + 2.f * y1 * z1;
    const float B20 = -2.f * w1 * y1 + 2.f * x1 * z1;
    const float B21 = 2.f * w1 * x1 + 2.f * y1 * z1;
    const float B22 = 1.f - 2.f * (x1 * x1 + y1 * y1);

    // --- loss_t partial: 50 scattered elements per block (wave 0) ---
    float lt = 0.f;
    if (tid < LT_PER_BLK) {
        int e = bid * LT_PER_BLK + tid;      // flat index into pred_t (8,500,3)
        int bb = e / 1500;
        int rem = e - bb * 1500;
        int n = rem / 3;
        int k = rem - n * 3;
        int pos = choose[bb * NP + n];
        float ts = target_t[(bb * 3 + k) * NHW + pos];
        float diff = pred_t[e] - ts;
        float ad = fabsf(diff);
        lt = (ad < 1.f) ? 0.5f * diff * diff : ad - 0.5f;
    }

    // --- reg term: wave 0 handles r0 (+lt reduce), wave 1 handles r1 ---
    if (tid < 64) {
        float dot = -BIGF;
        if (tid < NR) {
            const float* an = rot_anchors + tid * 4;
            dot = w0 * an[0] + x0 * an[1] + y0 * an[2] + z0 * an[3];
        }
        float diag = __shfl(dot, r0, 64);
        float mx = dot;
        for (int o = 32; o > 0; o >>= 1) mx = fmaxf(mx, __shfl_down(mx, o, 64));
        for (int o = 32; o > 0; o >>= 1) lt += __shfl_down(lt, o, 64);
        if (tid == 0) {
            float rg = mx - diag;
            out_reg[pair0] = (rg > 0.001f) ? rg : 0.f;
            out_lt[bid] = lt;
        }
    } else if (tid < 128) {
        float dot = -BIGF;
        if (ln < NR) {
            const float* an = rot_anchors + ln * 4;
            dot = w1 * an[0] + x1 * an[1] + y1 * an[2] + z1 * an[3];
        }
        float diag = __shfl(dot, r1, 64);
        float mx = dot;
        for (int o = 32; o > 0; o >>= 1) mx = fmaxf(mx, __shfl_down(mx, o, 64));
        if (ln == 0) {
            float rg = mx - diag;
            out_reg[pair0 + 1] = (rg > 0.001f) ? rg : 0.f;
        }
    }

    // --- rotate the 8 owned model points for both rotations; keep -2*p
    //     packed over k-pairs: nAx2[j] = {-2*pax(k=2j), -2*pax(k=2j+1)} ---
    v2f nAx2[4], nAy2[4], nAz2[4], nBx2[4], nBy2[4], nBz2[4];
    const float* mpb = model_points + b * NP * 3;
#pragma unroll
    for (int k = 0; k < 8; ++k) {
        int pt = k * 64 + ln;
        int pc = (pt < NP) ? pt : 0;         // clamp; masked at combine
        float mx_ = mpb[pc * 3 + 0], my_ = mpb[pc * 3 + 1], mz_ = mpb[pc * 3 + 2];
        float pax = A00 * mx_ + A01 * my_ + A02 * mz_;
        float pay = A10 * mx_ + A11 * my_ + A12 * mz_;
        float paz = A20 * mx_ + A21 * my_ + A22 * mz_;
        float pbx = B00 * mx_ + B01 * my_ + B02 * mz_;
        float pby = B10 * mx_ + B11 * my_ + B12 * mz_;
        float pbz = B20 * mx_ + B21 * my_ + B22 * mz_;
        nAx2[k >> 1][k & 1] = -2.f * pax;
        nAy2[k >> 1][k & 1] = -2.f * pay;
        nAz2[k >> 1][k & 1] = -2.f * paz;
        nBx2[k >> 1][k & 1] = -2.f * pbx;
        nBy2[k >> 1][k & 1] = -2.f * pby;
        nBz2[k >> 1][k & 1] = -2.f * pbz;
    }

    __syncthreads();                          // t4s ready

    // --- main loop: per-wave m-slice {62,62,62,62,62,62,64,64} (all even) ---
    const int mstart = (wv < 6) ? wv * 62 : 372 + (wv - 6) * 64;
    const int mend   = (wv < 6) ? mstart + 62 : mstart + 64;
    float mnA[8], mnB[8];
#pragma unroll
    for (int k = 0; k < 8; ++k) { mnA[k] = BIGF; mnB[k] = BIGF; }

    for (int m = mstart; m < mend; m += 2) {
        float4 t0 = t4s[m];                   // wave-uniform -> broadcast
        float4 t1 = t4s[m + 1];
        v2f t0x = {t0.x, t0.x}, t0y = {t0.y, t0.y}, t0z = {t0.z, t0.z}, t0w = {t0.w, t0.w};
        v2f t1x = {t1.x, t1.x}, t1y = {t1.y, t1.y}, t1z = {t1.z, t1.z}, t1w = {t1.w, t1.w};
#pragma unroll
        for (int j = 0; j < 4; ++j) {
            // d2 - |p|^2 = t.w - 2*p.t  (|p|^2 added back in epilogue)
            v2f dA0 = PKFMA(nAx2[j], t0x, PKFMA(nAy2[j], t0y, PKFMA(nAz2[j], t0z, t0w)));
            v2f dA1 = PKFMA(nAx2[j], t1x, PKFMA(nAy2[j], t1y, PKFMA(nAz2[j], t1z, t1w)));
            mnA[2 * j]     = fminf(mnA[2 * j],     fminf(dA0[0], dA1[0]));  // v_min3
            mnA[2 * j + 1] = fminf(mnA[2 * j + 1], fminf(dA0[1], dA1[1]));
            v2f dB0 = PKFMA(nBx2[j], t0x, PKFMA(nBy2[j], t0y, PKFMA(nBz2[j], t0z, t0w)));
            v2f dB1 = PKFMA(nBx2[j], t1x, PKFMA(nBy2[j], t1y, PKFMA(nBz2[j], t1z, t1w)));
            mnB[2 * j]     = fminf(mnB[2 * j],     fminf(dB0[0], dB1[0]));
            mnB[2 * j + 1] = fminf(mnB[2 * j + 1], fminf(dB0[1], dB1[1]));
        }
    }

    // --- publish partial mins ---
#pragma unroll
    for (int k = 0; k < 8; ++k)
        part2[(wv * 8 + k) * 64 + ln] = make_float2(mnA[k], mnB[k]);
    __syncthreads();

    // --- combine: wave 0 -> rotation A, wave 1 -> rotation B ---
    if (wv < 2) {
        const float* partf = (const float*)part2;
        float symsum = 0.f, nonsum = 0.f;
#pragma unroll
        for (int k = 0; k < 8; ++k) {
            float mn = BIGF;
#pragma unroll
            for (int w2 = 0; w2 < 8; ++w2) {
                float v = partf[((w2 * 8 + k) * 64 + ln) * 2 + wv];  // 2-way stride: free
                mn = fminf(mn, v);
            }
            float px = -0.5f * ((wv == 0) ? nAx2[k >> 1][k & 1] : nBx2[k >> 1][k & 1]);
            float py = -0.5f * ((wv == 0) ? nAy2[k >> 1][k & 1] : nBy2[k >> 1][k & 1]);
            float pz = -0.5f * ((wv == 0) ? nAz2[k >> 1][k & 1] : nBz2[k >> 1][k & 1]);
            float a2 = px * px + py * py + pz * pz;
            int pt = k * 64 + ln;
            if (pt < NP) {
                float d2 = fmaxf(a2 + mn, 1e-12f);
                symsum += sqrtf(d2);
                if (!symb) {                  // only needed when not symmetric
                    float4 t = t4s[pt];
                    float dx = px - t.x, dy = py - t.y, dz = pz - t.z;
                    nonsum += sqrtf(dx * dx + dy * dy + dz * dz);
                }
            }
        }
        for (int o = 32; o > 0; o >>= 1) {
            symsum += __shfl_down(symsum, o, 64);
            nonsum += __shfl_down(nonsum, o, 64);
        }
        if (ln == 0) {
            out_sym[pair0 + wv] = symsum;
            if (!symb) out_non[pair0 + wv] = nonsum;  // unread when symb
        }
    }

    // ================= fused finalize (last-block-done) =================
    __syncthreads();                          // all this block's stores issued+drained
    if (tid == 0) {
        __threadfence();                      // release: make partials device-visible
        unsigned int old = atomicAdd(&g_ctr, 1u);
        s_last = ((old % NBLK) == (NBLK - 1)) ? 1u : 0u;
    }
    __syncthreads();
    if (s_last == 0u) return;

    __threadfence();                          // acquire: invalidate stale L1/L2 lines
    float s_r = 0.f, s_reg = 0.f, s_t = 0.f;
    if (tid < NPAIR) {                        // 480 < 512: one element per thread
        int bb2 = tid / NR;
        bool sym2 = (symU8[bb2] != 0) || (symI[bb2] != 0);
        float sum = sym2 ? out_sym[tid] : out_non[tid];
        float dd = sum * (1.0f / NP);
        float c = pred_c[tid];
        s_r = (dd / (diam[bb2] * c) + logf(c)) * (1.0f / NR);
        s_reg = out_reg[tid];
    }
    if (tid < NBLK) s_t = out_lt[tid];

    for (int o = 32; o > 0; o >>= 1) {
        s_r  += __shfl_down(s_r, o, 64);
        s_reg += __shfl_down(s_reg, o, 64);
        s_t  += __shfl_down(s_t, o, 64);
    }
    float* red = (float*)part2;               // reuse LDS (safe: past all readers)
    if (ln == 0) { red[wv] = s_r; red[8 + wv] = s_reg; red[16 + wv] = s_t; }
    __syncthreads();
    if (tid == 0) {
        float lr = 0.f, lreg = 0.f, ltv = 0.f;
#pragma unroll
        for (int w2 = 0; w2 < 8; ++w2) {
            lr += red[w2]; lreg += red[8 + w2]; ltv += red[16 + w2];
        }
        lreg *= (1.0f / NPAIR);
        ltv  *= (1.0f / NT_ELEMS);
        out[0] = lr + 2.f * lreg + 5.f * ltv;
        out[1] = lr;
        out[2] = lreg;
        out[3] = ltv;
    }
}

extern "C" void kernel_launch(void* const* d_in, const int* in_sizes, int n_in,
                              void* d_out, int out_size, void* d_ws, size_t ws_size,
                              hipStream_t stream) {
    const float* pred_t       = (const float*)d_in[0];
    const float* pred_r       = (const float*)d_in[1];
    const float* pred_c       = (const float*)d_in[2];
    const float* target_r     = (const float*)d_in[3];
    const float* target_t     = (const float*)d_in[4];
    const float* model_points = (const float*)d_in[5];
    const int*   choose       = (const int*)d_in[6];
    const unsigned char* symU8 = (const unsigned char*)d_in[7];
    const int*   symI         = (const int*)d_in[7];
    const float* diam         = (const float*)d_in[8];
    const float* anchors      = (const float*)d_in[9];
    float* out = (float*)d_out;

    char* ws = (char*)d_ws;
    float* o_sym = (float*)ws;                        // 480 floats
    float* o_non = o_sym + NPAIR;                     // 480
    float* o_reg = o_non + NPAIR;                     // 480
    float* o_lt  = o_reg + NPAIR;                     // 240

    main_kernel<<<NBLK, 512, 0, stream>>>(pred_t, pred_r, target_r, target_t,
                                          model_points, choose, anchors,
                                          pred_c, symU8, symI, diam,
                                          o_sym, o_non, o_reg, o_lt, out);
}